// Round 1
// baseline (316.151 us; speedup 1.0000x reference)
//
#include <hip/hip_runtime.h>
#include <math.h>

// Problem constants: B=8, S=1024, D=128 (fp32 everywhere)
#define NB 8
#define NS 1024
#define ND 128

// workspace layout (float offsets)
#define OFF_K  0u
#define OFF_Q  1048576u
#define OFF_V  2097152u
#define OFF_E  3145728u
#define OFF_GA 4194304u
#define OFF_GE 4202496u
#define OFF_GT 4210688u
#define OFF_W  4218880u
#define OFF_C  4227072u
#define OFF_P  4235264u   // 4 * 262144 partials

// ---------------------------------------------------------------------------
// Kernel A: k = x@Wk, v = x@Wv, q = x@Wq, gates = sigmoid(x@Wg + bg)
// grid 512 blocks (16 rows each), 256 threads. x tile staged in LDS.
// Thread (c = tid&127, g = tid>>7) computes 8 rows x {k,v,q} for column c.
// ---------------------------------------------------------------------------
__global__ __launch_bounds__(256) void proj_kernel(
    const float* __restrict__ x,  const float* __restrict__ Wk,
    const float* __restrict__ Wv, const float* __restrict__ Wq,
    const float* __restrict__ Wg, const float* __restrict__ bg,
    float* __restrict__ Kb, float* __restrict__ Vb, float* __restrict__ Qb,
    float* __restrict__ ga, float* __restrict__ ge, float* __restrict__ gt)
{
    __shared__ float xs[16 * 132];   // padded rows: conflict-free writes, broadcast reads
    const int tid  = threadIdx.x;
    const int row0 = blockIdx.x * 16;

#pragma unroll
    for (int l = 0; l < 8; ++l) {
        int idx = tid + l * 256;          // 0..2047
        int r = idx >> 7, i = idx & 127;
        xs[r * 132 + i] = x[(row0 + r) * ND + i];
    }
    __syncthreads();

    const int c = tid & 127;
    const int g = tid >> 7;               // 0 or 1 -> rows g*8 .. g*8+7
    float ak[8], av[8], aq[8];
#pragma unroll
    for (int r = 0; r < 8; ++r) { ak[r] = 0.f; av[r] = 0.f; aq[r] = 0.f; }

    const float* xrow = &xs[g * 8 * 132];
#pragma unroll 4
    for (int i = 0; i < ND; ++i) {
        float wk = Wk[i * ND + c];
        float wv = Wv[i * ND + c];
        float wq = Wq[i * ND + c];
#pragma unroll
        for (int r = 0; r < 8; ++r) {
            float xr = xrow[r * 132 + i];     // LDS broadcast within half-block
            ak[r] = fmaf(xr, wk, ak[r]);
            av[r] = fmaf(xr, wv, av[r]);
            aq[r] = fmaf(xr, wq, aq[r]);
        }
    }
#pragma unroll
    for (int r = 0; r < 8; ++r) {
        int row = row0 + g * 8 + r;
        Kb[row * ND + c] = ak[r];
        Vb[row * ND + c] = av[r];
        Qb[row * ND + c] = aq[r];
    }

    // gates: 48 threads, one (row r, gate j) each
    if (tid < 48) {
        int r = tid / 3, j = tid % 3;
        float z = bg[j];
#pragma unroll 4
        for (int i = 0; i < ND; ++i)
            z = fmaf(xs[r * 132 + i], Wg[i * 3 + j], z);
        float gate = 1.0f / (1.0f + expf(-z));
        int row = row0 + r;
        float* dst = (j == 0) ? ga : (j == 1) ? ge : gt;
        dst[row] = gate;
    }
}

// ---------------------------------------------------------------------------
// Kernel B: diagonal scan (y_t, err_t) + backward coefficient scan (w_t, c_t)
// 8 blocks (one per batch), 192 threads (3 waves).
//   tid 0..127 : per-d scalar recurrence  m' = (1-a)m + s',  s' = e s - θk(km - v)
//   tid 128    : backward scan  P_t=(1-a_{t+1})P_{t+1}, A_t=P_t+e_{t+1}A_{t+1},
//                Q_t=e_{t+1}Q_{t+1};  w_t=-θ_t Q_t,  c_t=-θ_t A_t
// ---------------------------------------------------------------------------
__global__ __launch_bounds__(192) void scan_kernel(
    const float* __restrict__ Kb, const float* __restrict__ Vb,
    const float* __restrict__ Qb,
    const float* __restrict__ ga, const float* __restrict__ ge,
    const float* __restrict__ gt,
    float* __restrict__ out, float* __restrict__ errb,
    float* __restrict__ wb,  float* __restrict__ cb)
{
    __shared__ float la[NS], le[NS], ltt[NS];
    const int b   = blockIdx.x;
    const int tid = threadIdx.x;

    for (int i = tid; i < NS; i += 192) {
        la[i]  = ga[b * NS + i];
        le[i]  = ge[b * NS + i];
        ltt[i] = gt[b * NS + i];
    }
    __syncthreads();

    if (tid < 128) {
        const int d = tid;
        int base = b * (NS * ND) + d;
        float m = 0.f, s = 0.f;
#pragma unroll 2
        for (int t = 0; t < NS; ++t) {
            float k = Kb[base], v = Vb[base], q = Qb[base];
            float a = la[t], e = le[t], th = ltt[t];
            float err = fmaf(k, m, -v);        // k*m_{t-1} - v
            out[base]  = q * m;                // y_t = q * diag(M_{t-1})
            errb[base] = err;
            float tk = th * k;
            float u  = fmaf(-(tk * k), m, tk * v);  // -θk²m + θkv
            s = fmaf(e, s, u);                 // s_t
            m = fmaf(1.0f - a, m, s);          // m_t
            base += ND;
        }
    } else if (tid == 128) {
        const int bt = b * NS;
        float Qp = 1.f, P = 1.f, A = 1.f;
        wb[bt + NS - 1] = -ltt[NS - 1];
        cb[bt + NS - 1] = -ltt[NS - 1];
#pragma unroll 8
        for (int t = NS - 2; t >= 0; --t) {
            float e1 = le[t + 1], a1 = la[t + 1], th = ltt[t];
            Qp *= e1;
            P  *= (1.0f - a1);
            A   = fmaf(e1, A, P);
            wb[bt + t] = -th * Qp;
            cb[bt + t] = -th * A;
        }
    }
}

// ---------------------------------------------------------------------------
// Kernel C: M_final/S_final partials.  C[i][j] = Σ_t coeff_t k_t[i] err_t[j]
// grid = 8b × 4 t-chunks × 8 row-groups = 256 blocks, 256 threads.
// Each thread: col j, 8 rows → 16 accumulators; k-tile + w/c staged in LDS.
// ---------------------------------------------------------------------------
__global__ __launch_bounds__(256) void finalgemm_kernel(
    const float* __restrict__ Kb, const float* __restrict__ errb,
    const float* __restrict__ wb, const float* __restrict__ cb,
    float* __restrict__ part)
{
    __shared__ float ks[256 * 16];
    __shared__ float wcs[256 * 2];
    const int tid = threadIdx.x;
    const int bid = blockIdx.x;
    const int b   = bid >> 5;
    const int tc  = (bid >> 3) & 3;
    const int rg  = bid & 7;
    const int bt0 = b * NS + tc * 256;

#pragma unroll
    for (int l = 0; l < 16; ++l) {
        int idx = tid + l * 256;          // 0..4095
        int tl = idx >> 4, r = idx & 15;
        ks[tl * 16 + r] = Kb[(bt0 + tl) * ND + rg * 16 + r];
    }
    wcs[tid * 2]     = wb[bt0 + tid];
    wcs[tid * 2 + 1] = cb[bt0 + tid];
    __syncthreads();

    const int j = tid & 127;
    const int h = tid >> 7;               // 0/1 -> rows rg*16 + h*8 ..
    float accM[8], accS[8];
#pragma unroll
    for (int i = 0; i < 8; ++i) { accM[i] = 0.f; accS[i] = 0.f; }

    int ebase = bt0 * ND + j;
#pragma unroll 2
    for (int t = 0; t < 256; ++t) {
        float ej = errb[ebase];
        float2 wc = *(const float2*)&wcs[t * 2];
        float wej = wc.x * ej, cej = wc.y * ej;
        float4 k0 = *(const float4*)&ks[t * 16 + h * 8];
        float4 k1 = *(const float4*)&ks[t * 16 + h * 8 + 4];
        accS[0] = fmaf(k0.x, wej, accS[0]); accM[0] = fmaf(k0.x, cej, accM[0]);
        accS[1] = fmaf(k0.y, wej, accS[1]); accM[1] = fmaf(k0.y, cej, accM[1]);
        accS[2] = fmaf(k0.z, wej, accS[2]); accM[2] = fmaf(k0.z, cej, accM[2]);
        accS[3] = fmaf(k0.w, wej, accS[3]); accM[3] = fmaf(k0.w, cej, accM[3]);
        accS[4] = fmaf(k1.x, wej, accS[4]); accM[4] = fmaf(k1.x, cej, accM[4]);
        accS[5] = fmaf(k1.y, wej, accS[5]); accM[5] = fmaf(k1.y, cej, accM[5]);
        accS[6] = fmaf(k1.z, wej, accS[6]); accM[6] = fmaf(k1.z, cej, accM[6]);
        accS[7] = fmaf(k1.w, wej, accS[7]); accM[7] = fmaf(k1.w, cej, accM[7]);
        ebase += ND;
    }

    const int robase = rg * 16 + h * 8;
    const unsigned pb = (unsigned)tc * 262144u;
#pragma unroll
    for (int i = 0; i < 8; ++i) {
        int off = b * (ND * ND) + (robase + i) * ND + j;
        part[pb + off]           = accM[i];
        part[pb + 131072u + off] = accS[i];
    }
}

// ---------------------------------------------------------------------------
// Kernel D: reduce 4 t-chunk partials into d_out tail (M_final then S_final)
// ---------------------------------------------------------------------------
__global__ __launch_bounds__(256) void reduce_kernel(
    const float* __restrict__ part, float* __restrict__ outMS)
{
    int idx = blockIdx.x * 256 + threadIdx.x;   // 0..65535 float4s
    const float4* p = (const float4*)part;
    float4 a = p[idx];
    float4 b = p[idx + 65536];
    float4 c = p[idx + 131072];
    float4 d = p[idx + 196608];
    float4 r;
    r.x = a.x + b.x + c.x + d.x;
    r.y = a.y + b.y + c.y + d.y;
    r.z = a.z + b.z + c.z + d.z;
    r.w = a.w + b.w + c.w + d.w;
    ((float4*)outMS)[idx] = r;
}

extern "C" void kernel_launch(void* const* d_in, const int* in_sizes, int n_in,
                              void* d_out, int out_size, void* d_ws, size_t ws_size,
                              hipStream_t stream) {
    const float* x  = (const float*)d_in[0];
    const float* Wk = (const float*)d_in[1];
    const float* Wv = (const float*)d_in[2];
    const float* Wq = (const float*)d_in[3];
    const float* Wg = (const float*)d_in[4];
    const float* bg = (const float*)d_in[5];
    float* out = (float*)d_out;
    float* ws  = (float*)d_ws;

    float* Kb  = ws + OFF_K;
    float* Qb  = ws + OFF_Q;
    float* Vb  = ws + OFF_V;
    float* Eb  = ws + OFF_E;
    float* ga  = ws + OFF_GA;
    float* ge  = ws + OFF_GE;
    float* gt  = ws + OFF_GT;
    float* wbf = ws + OFF_W;
    float* cbf = ws + OFF_C;
    float* Pb  = ws + OFF_P;

    proj_kernel<<<512, 256, 0, stream>>>(x, Wk, Wv, Wq, Wg, bg,
                                         Kb, Vb, Qb, ga, ge, gt);
    scan_kernel<<<NB, 192, 0, stream>>>(Kb, Vb, Qb, ga, ge, gt,
                                        out, Eb, wbf, cbf);
    finalgemm_kernel<<<256, 256, 0, stream>>>(Kb, Eb, wbf, cbf, Pb);
    reduce_kernel<<<256, 256, 0, stream>>>(Pb, out + 1048576u);
}

// Round 3
// 173.083 us; speedup vs baseline: 1.8266x; 1.8266x over previous
//
#include <hip/hip_runtime.h>
#include <math.h>

// Problem constants: B=8, S=1024, D=128 (fp32 everywhere)
#define NB 8
#define NS 1024
#define ND 128
#define NC 64     // chunks
#define NL 16     // steps per chunk

// workspace layout (float offsets)
#define OFF_K  0u
#define OFF_Q  1048576u
#define OFF_V  2097152u
#define OFF_E  3145728u
#define OFF_GA 4194304u
#define OFF_GE 4202496u
#define OFF_GT 4210688u
#define OFF_W  4218880u
#define OFF_C  4227072u
#define OFF_P  4235264u   // 4 * 262144 partials; scan scratch aliases this

// chunked-scan scratch, aliased into the partials region (dead before finalgemm)
#define PL_A00 (OFF_P)
#define PL_A01 (OFF_P +  65536u)
#define PL_A10 (OFF_P + 131072u)
#define PL_A11 (OFF_P + 196608u)
#define PL_B0  (OFF_P + 262144u)
#define PL_B1  (OFF_P + 327680u)
#define PL_MST (OFF_P + 393216u)
#define PL_SST (OFF_P + 458752u)
#define PL_WCA (OFF_P + 524288u)
#define PL_WCB (OFF_P + 524800u)
#define PL_WCD (OFF_P + 525312u)
#define PL_WRQ (OFF_P + 525824u)
#define PL_WRP (OFF_P + 526336u)
#define PL_WRA (OFF_P + 526848u)

// ---------------------------------------------------------------------------
// Kernel A: k = x@Wk, v = x@Wv, q = x@Wq, gates = sigmoid(x@Wg + bg)
// ---------------------------------------------------------------------------
__global__ __launch_bounds__(256) void proj_kernel(
    const float* __restrict__ x,  const float* __restrict__ Wk,
    const float* __restrict__ Wv, const float* __restrict__ Wq,
    const float* __restrict__ Wg, const float* __restrict__ bg,
    float* __restrict__ Kb, float* __restrict__ Vb, float* __restrict__ Qb,
    float* __restrict__ ga, float* __restrict__ ge, float* __restrict__ gt)
{
    __shared__ float xs[16 * 132];
    const int tid  = threadIdx.x;
    const int row0 = blockIdx.x * 16;

#pragma unroll
    for (int l = 0; l < 8; ++l) {
        int idx = tid + l * 256;
        int r = idx >> 7, i = idx & 127;
        xs[r * 132 + i] = x[(row0 + r) * ND + i];
    }
    __syncthreads();

    const int c = tid & 127;
    const int g = tid >> 7;
    float ak[8], av[8], aq[8];
#pragma unroll
    for (int r = 0; r < 8; ++r) { ak[r] = 0.f; av[r] = 0.f; aq[r] = 0.f; }

    const float* xrow = &xs[g * 8 * 132];
#pragma unroll 4
    for (int i = 0; i < ND; ++i) {
        float wk = Wk[i * ND + c];
        float wv = Wv[i * ND + c];
        float wq = Wq[i * ND + c];
#pragma unroll
        for (int r = 0; r < 8; ++r) {
            float xr = xrow[r * 132 + i];
            ak[r] = fmaf(xr, wk, ak[r]);
            av[r] = fmaf(xr, wv, av[r]);
            aq[r] = fmaf(xr, wq, aq[r]);
        }
    }
#pragma unroll
    for (int r = 0; r < 8; ++r) {
        int row = row0 + g * 8 + r;
        Kb[row * ND + c] = ak[r];
        Vb[row * ND + c] = av[r];
        Qb[row * ND + c] = aq[r];
    }

    if (tid < 48) {
        int r = tid / 3, j = tid % 3;
        float z = bg[j];
#pragma unroll 4
        for (int i = 0; i < ND; ++i)
            z = fmaf(xs[r * 132 + i], Wg[i * 3 + j], z);
        float gate = 1.0f / (1.0f + expf(-z));
        int row = row0 + r;
        float* dst = (j == 0) ? ga : (j == 1) ? ge : gt;
        dst[row] = gate;
    }
}

// ---------------------------------------------------------------------------
// Phase 1: per (b, chunk, d) compose the 16 per-step affine maps into (A, b).
// Per-step (forward m/s): m' = p*m + e*s + h ; s' = g*m + e*s + h
//   with g = -theta*k^2, p = (1-a)+g, h = theta*k*v
// Thread 0 also composes the backward wc map over the chunk (emit-then-update
// form, gates at index t itself):
//   step t: Qp' = e_t*Qp, P' = (1-a_t)*P, A' = e_t*A + P'
//   chunk composite: Qp_out = al*Qp_in, P_out = be*P_in,
//                    A_out = al*A_in + de*P_in
// ---------------------------------------------------------------------------
__global__ __launch_bounds__(128) void scan_phase1(
    const float* __restrict__ Kb, const float* __restrict__ Vb,
    const float* __restrict__ ga, const float* __restrict__ ge,
    const float* __restrict__ gt, float* __restrict__ ws)
{
    __shared__ float la[NL], le[NL], lt[NL];
    const int tid = threadIdx.x;
    const int b   = blockIdx.x >> 6;
    const int c   = blockIdx.x & 63;
    const int t0  = c * NL;
    const int g0  = b * NS + t0;

    if (tid < 16)       la[tid]      = ga[g0 + tid];
    else if (tid < 32)  le[tid - 16] = ge[g0 + tid - 16];
    else if (tid < 48)  lt[tid - 32] = gt[g0 + tid - 32];
    __syncthreads();

    const int d = tid;
    float A00 = 1.f, A01 = 0.f, A10 = 0.f, A11 = 1.f, B0 = 0.f, B1 = 0.f;
    int base = g0 * ND + d;
#pragma unroll
    for (int t = 0; t < NL; ++t) {
        float k = Kb[base], v = Vb[base];
        float a = la[t], e = le[t], th = lt[t];
        float tk = th * k;
        float gg = -tk * k;
        float h  = tk * v;
        float p  = (1.0f - a) + gg;
        float u0 = e * A10;
        float u1 = e * A11;
        float u2 = fmaf(e, B1, h);
        float n00 = fmaf(p, A00, u0), n10 = fmaf(gg, A00, u0);
        float n01 = fmaf(p, A01, u1), n11 = fmaf(gg, A01, u1);
        float nb0 = fmaf(p, B0, u2),  nb1 = fmaf(gg, B0, u2);
        A00 = n00; A01 = n01; A10 = n10; A11 = n11; B0 = nb0; B1 = nb1;
        base += ND;
    }
    const int pidx = (b * NC + c) * ND + d;
    ws[PL_A00 + pidx] = A00;
    ws[PL_A01 + pidx] = A01;
    ws[PL_A10 + pidx] = A10;
    ws[PL_A11 + pidx] = A11;
    ws[PL_B0  + pidx] = B0;
    ws[PL_B1  + pidx] = B1;

    if (tid == 0) {
        // backward composite over t = NL-1 .. 0 with gates at index t
        float al = 1.f, be = 1.f, de = 0.f;
#pragma unroll
        for (int t = NL - 1; t >= 0; --t) {
            float e1 = le[t];
            float o1 = 1.0f - la[t];
            de = fmaf(e1, de, o1 * be);
            al *= e1;
            be *= o1;
        }
        ws[PL_WCA + b * NC + c] = al;
        ws[PL_WCB + b * NC + c] = be;
        ws[PL_WCD + b * NC + c] = de;
    }
}

// ---------------------------------------------------------------------------
// Phase 2: scan over chunks.
// Blocks 0..15: chain (b,d): state (m,s) across 64 chunks, storing the state
//               ENTERING each chunk.  Block 16 (threads 0..7): backward wc
//               chunk scan per batch, storing the state entering each chunk
//               from the right (seed (1,1,1) at chunk NC-1).
// ---------------------------------------------------------------------------
__global__ __launch_bounds__(64) void scan_phase2(float* __restrict__ ws)
{
    const int tid = threadIdx.x;
    if (blockIdx.x < 16) {
        const int b = blockIdx.x >> 1;
        const int d = (blockIdx.x & 1) * 64 + tid;
        float m = 0.f, s = 0.f;
        int idx = (b * NC) * ND + d;
#pragma unroll 4
        for (int c = 0; c < NC; ++c) {
            ws[PL_MST + idx] = m;
            ws[PL_SST + idx] = s;
            float A00 = ws[PL_A00 + idx], A01 = ws[PL_A01 + idx];
            float A10 = ws[PL_A10 + idx], A11 = ws[PL_A11 + idx];
            float B0  = ws[PL_B0  + idx], B1  = ws[PL_B1  + idx];
            float nm = fmaf(A00, m, fmaf(A01, s, B0));
            float ns = fmaf(A10, m, fmaf(A11, s, B1));
            m = nm; s = ns;
            idx += ND;
        }
    } else if (tid < 8) {
        const int b = tid;
        float Qp = 1.f, P = 1.f, A = 1.f;
        for (int c = NC - 1; c >= 0; --c) {
            ws[PL_WRQ + b * NC + c] = Qp;
            ws[PL_WRP + b * NC + c] = P;
            ws[PL_WRA + b * NC + c] = A;
            float al = ws[PL_WCA + b * NC + c];
            float be = ws[PL_WCB + b * NC + c];
            float de = ws[PL_WCD + b * NC + c];
            float nA = fmaf(al, A, de * P);
            Qp *= al; P *= be; A = nA;
        }
    }
}

// ---------------------------------------------------------------------------
// Phase 3: replay each chunk from its known start state; emit y_t, err_t.
// Thread 0 replays the wc backward recurrence (emit-then-update) emitting
// w_t, c_t.
// ---------------------------------------------------------------------------
__global__ __launch_bounds__(128) void scan_phase3(
    const float* __restrict__ Kb, const float* __restrict__ Vb,
    const float* __restrict__ Qb,
    const float* __restrict__ ga, const float* __restrict__ ge,
    const float* __restrict__ gt,
    float* __restrict__ out, float* __restrict__ errb,
    float* __restrict__ wb,  float* __restrict__ cb,
    float* __restrict__ ws)
{
    __shared__ float la[NL], le[NL], lt[NL];
    const int tid = threadIdx.x;
    const int b   = blockIdx.x >> 6;
    const int c   = blockIdx.x & 63;
    const int t0  = c * NL;
    const int g0  = b * NS + t0;

    if (tid < 16)       la[tid]      = ga[g0 + tid];
    else if (tid < 32)  le[tid - 16] = ge[g0 + tid - 16];
    else if (tid < 48)  lt[tid - 32] = gt[g0 + tid - 32];
    __syncthreads();

    const int d = tid;
    const int pidx = (b * NC + c) * ND + d;
    float m = ws[PL_MST + pidx];
    float s = ws[PL_SST + pidx];
    int base = g0 * ND + d;
#pragma unroll
    for (int t = 0; t < NL; ++t) {
        float k = Kb[base], v = Vb[base], q = Qb[base];
        float a = la[t], e = le[t], th = lt[t];
        float err = fmaf(k, m, -v);
        out[base]  = q * m;
        errb[base] = err;
        float tk = th * k;
        float u  = fmaf(-(tk * k), m, tk * v);
        s = fmaf(e, s, u);
        m = fmaf(1.0f - a, m, s);
        base += ND;
    }

    if (tid == 0) {
        float Qp = ws[PL_WRQ + b * NC + c];
        float P  = ws[PL_WRP + b * NC + c];
        float A  = ws[PL_WRA + b * NC + c];
#pragma unroll
        for (int t = NL - 1; t >= 0; --t) {
            // emit from current state
            wb[g0 + t] = -lt[t] * Qp;
            cb[g0 + t] = -lt[t] * A;
            // then advance with gates at index t
            float e1 = le[t];
            float o1 = 1.0f - la[t];
            Qp *= e1;
            P  *= o1;
            A   = fmaf(e1, A, P);
        }
    }
}

// ---------------------------------------------------------------------------
// Kernel C: M_final/S_final partials.  C[i][j] = sum_t coeff_t k_t[i] err_t[j]
// ---------------------------------------------------------------------------
__global__ __launch_bounds__(256) void finalgemm_kernel(
    const float* __restrict__ Kb, const float* __restrict__ errb,
    const float* __restrict__ wb, const float* __restrict__ cb,
    float* __restrict__ part)
{
    __shared__ float ks[256 * 16];
    __shared__ float wcs[256 * 2];
    const int tid = threadIdx.x;
    const int bid = blockIdx.x;
    const int b   = bid >> 5;
    const int tc  = (bid >> 3) & 3;
    const int rg  = bid & 7;
    const int bt0 = b * NS + tc * 256;

#pragma unroll
    for (int l = 0; l < 16; ++l) {
        int idx = tid + l * 256;
        int tl = idx >> 4, r = idx & 15;
        ks[tl * 16 + r] = Kb[(bt0 + tl) * ND + rg * 16 + r];
    }
    wcs[tid * 2]     = wb[bt0 + tid];
    wcs[tid * 2 + 1] = cb[bt0 + tid];
    __syncthreads();

    const int j = tid & 127;
    const int h = tid >> 7;
    float accM[8], accS[8];
#pragma unroll
    for (int i = 0; i < 8; ++i) { accM[i] = 0.f; accS[i] = 0.f; }

    int ebase = bt0 * ND + j;
#pragma unroll 2
    for (int t = 0; t < 256; ++t) {
        float ej = errb[ebase];
        float2 wc = *(const float2*)&wcs[t * 2];
        float wej = wc.x * ej, cej = wc.y * ej;
        float4 k0 = *(const float4*)&ks[t * 16 + h * 8];
        float4 k1 = *(const float4*)&ks[t * 16 + h * 8 + 4];
        accS[0] = fmaf(k0.x, wej, accS[0]); accM[0] = fmaf(k0.x, cej, accM[0]);
        accS[1] = fmaf(k0.y, wej, accS[1]); accM[1] = fmaf(k0.y, cej, accM[1]);
        accS[2] = fmaf(k0.z, wej, accS[2]); accM[2] = fmaf(k0.z, cej, accM[2]);
        accS[3] = fmaf(k0.w, wej, accS[3]); accM[3] = fmaf(k0.w, cej, accM[3]);
        accS[4] = fmaf(k1.x, wej, accS[4]); accM[4] = fmaf(k1.x, cej, accM[4]);
        accS[5] = fmaf(k1.y, wej, accS[5]); accM[5] = fmaf(k1.y, cej, accM[5]);
        accS[6] = fmaf(k1.z, wej, accS[6]); accM[6] = fmaf(k1.z, cej, accM[6]);
        accS[7] = fmaf(k1.w, wej, accS[7]); accM[7] = fmaf(k1.w, cej, accM[7]);
        ebase += ND;
    }

    const int robase = rg * 16 + h * 8;
    const unsigned pb = (unsigned)tc * 262144u;
#pragma unroll
    for (int i = 0; i < 8; ++i) {
        int off = b * (ND * ND) + (robase + i) * ND + j;
        part[pb + off]           = accM[i];
        part[pb + 131072u + off] = accS[i];
    }
}

// ---------------------------------------------------------------------------
// Kernel D: reduce 4 t-chunk partials into d_out tail (M_final then S_final)
// ---------------------------------------------------------------------------
__global__ __launch_bounds__(256) void reduce_kernel(
    const float* __restrict__ part, float* __restrict__ outMS)
{
    int idx = blockIdx.x * 256 + threadIdx.x;
    const float4* p = (const float4*)part;
    float4 a = p[idx];
    float4 b = p[idx + 65536];
    float4 c = p[idx + 131072];
    float4 d = p[idx + 196608];
    float4 r;
    r.x = a.x + b.x + c.x + d.x;
    r.y = a.y + b.y + c.y + d.y;
    r.z = a.z + b.z + c.z + d.z;
    r.w = a.w + b.w + c.w + d.w;
    ((float4*)outMS)[idx] = r;
}

extern "C" void kernel_launch(void* const* d_in, const int* in_sizes, int n_in,
                              void* d_out, int out_size, void* d_ws, size_t ws_size,
                              hipStream_t stream) {
    const float* x  = (const float*)d_in[0];
    const float* Wk = (const float*)d_in[1];
    const float* Wv = (const float*)d_in[2];
    const float* Wq = (const float*)d_in[3];
    const float* Wg = (const float*)d_in[4];
    const float* bg = (const float*)d_in[5];
    float* out = (float*)d_out;
    float* ws  = (float*)d_ws;

    float* Kb  = ws + OFF_K;
    float* Qb  = ws + OFF_Q;
    float* Vb  = ws + OFF_V;
    float* Eb  = ws + OFF_E;
    float* ga  = ws + OFF_GA;
    float* ge  = ws + OFF_GE;
    float* gt  = ws + OFF_GT;
    float* wbf = ws + OFF_W;
    float* cbf = ws + OFF_C;
    float* Pb  = ws + OFF_P;

    proj_kernel<<<512, 256, 0, stream>>>(x, Wk, Wv, Wq, Wg, bg,
                                         Kb, Vb, Qb, ga, ge, gt);
    scan_phase1<<<NB * NC, 128, 0, stream>>>(Kb, Vb, ga, ge, gt, ws);
    scan_phase2<<<17, 64, 0, stream>>>(ws);
    scan_phase3<<<NB * NC, 128, 0, stream>>>(Kb, Vb, Qb, ga, ge, gt,
                                             out, Eb, wbf, cbf, ws);
    finalgemm_kernel<<<256, 256, 0, stream>>>(Kb, Eb, wbf, cbf, Pb);
    reduce_kernel<<<256, 256, 0, stream>>>(Pb, out + 1048576u);
}

// Round 5
// 139.086 us; speedup vs baseline: 2.2731x; 1.2444x over previous
//
#include <hip/hip_runtime.h>
#include <math.h>

// Problem constants: B=8, S=1024, D=128 (fp32 in/out)
#define NB 8
#define NS 1024
#define ND 128
#define NC 64     // chunks
#define NL 16     // steps per chunk

// workspace layout (float offsets)
#define OFF_K  0u
#define OFF_Q  1048576u
#define OFF_V  2097152u
#define OFF_E  3145728u
#define OFF_GA 4194304u
#define OFF_GE 4202496u
#define OFF_GT 4210688u
#define OFF_W  4218880u
#define OFF_C  4227072u
#define OFF_P  4235264u   // 4 * 262144 partials; scan scratch aliases this

// chunked-scan scratch, aliased into the partials region (dead before finalgemm)
#define PL_A00 (OFF_P)
#define PL_A01 (OFF_P +  65536u)
#define PL_A10 (OFF_P + 131072u)
#define PL_A11 (OFF_P + 196608u)
#define PL_B0  (OFF_P + 262144u)
#define PL_B1  (OFF_P + 327680u)
#define PL_MST (OFF_P + 393216u)
#define PL_SST (OFF_P + 458752u)
#define PL_WCA (OFF_P + 524288u)
#define PL_WCB (OFF_P + 524800u)
#define PL_WCD (OFF_P + 525312u)
#define PL_WRQ (OFF_P + 525824u)
#define PL_WRP (OFF_P + 526336u)
#define PL_WRA (OFF_P + 526848u)
// bf16 W^T hi+lo (3 mats x 128 cols x 128 k each), ushort; 49152 floats space
#define OFF_WT (OFF_P + 532480u)
#define WT_LO  49152u   // ushort offset of lo plane

typedef short bf16x8 __attribute__((ext_vector_type(8)));
typedef float f32x4  __attribute__((ext_vector_type(4)));

static __device__ __forceinline__ unsigned short f2bf(float f) {
    unsigned u = __builtin_bit_cast(unsigned, f);
    unsigned r = (u + 0x7FFFu + ((u >> 16) & 1u)) >> 16;   // RNE
    return (unsigned short)r;
}
static __device__ __forceinline__ float bf2f(unsigned short h) {
    unsigned u = ((unsigned)h) << 16;
    return __builtin_bit_cast(float, u);
}
static __device__ __forceinline__ unsigned pack2(float a, float b) {
    return (unsigned)f2bf(a) | ((unsigned)f2bf(b) << 16);
}
// split f into hi (bf16) and lo (bf16 of residual)
static __device__ __forceinline__ void split2(float a, float b,
                                              unsigned& hi, unsigned& lo) {
    unsigned short ah = f2bf(a), bh = f2bf(b);
    float ar = a - bf2f(ah), br = b - bf2f(bh);
    hi = (unsigned)ah | ((unsigned)bh << 16);
    lo = (unsigned)f2bf(ar) | ((unsigned)f2bf(br) << 16);
}

// ---------------------------------------------------------------------------
// wtprep: W[k][c] fp32 -> wtg hi/lo planes [m][c][k] bf16 (transposed)
// grid 48 = 3 mats x 16 col-groups(8); thread (cl=tid>>5, h=tid&31), k=h*4+i.
// ---------------------------------------------------------------------------
__global__ __launch_bounds__(256) void wtprep_kernel(
    const float* __restrict__ Wk, const float* __restrict__ Wv,
    const float* __restrict__ Wq, unsigned short* __restrict__ wtg)
{
    const int m    = blockIdx.x >> 4;
    const int cgrp = blockIdx.x & 15;
    const int tid  = threadIdx.x;
    const int cl   = tid >> 5;
    const int h    = tid & 31;
    const int c    = cgrp * 8 + cl;
    const float* W = (m == 0) ? Wk : (m == 1) ? Wv : Wq;

    float f[4];
#pragma unroll
    for (int i = 0; i < 4; ++i)
        f[i] = W[(h * 4 + i) * ND + c];
    uint2 hi, lo;
    split2(f[0], f[1], hi.x, lo.x);
    split2(f[2], f[3], hi.y, lo.y);
    const unsigned base = (unsigned)m * 16384u + (unsigned)c * 128u + (unsigned)h * 4u;
    *(uint2*)&wtg[base]         = hi;
    *(uint2*)&wtg[WT_LO + base] = lo;
}

// ---------------------------------------------------------------------------
// proj_mfma: one of {k,v,q} = x @ W via split-bf16 MFMA 16x16x32
// (3 MFMA terms: hi*hi + hi*lo + lo*hi -> ~fp32 precision).
// grid 1536 = 3 mats x 256 row-tiles(32) x 2 col-halves(64). 256 thr = 4 waves,
// wave (rg=wid>>1, cg=wid&1): rows rg*16.., cols cg*32.. (2 tiles, K=128).
// (m==0,ch==0) blocks also compute the 3 sigmoid gates for their rows (fp32).
// ---------------------------------------------------------------------------
__global__ __launch_bounds__(256) void proj_mfma(
    const float* __restrict__ x, const unsigned short* __restrict__ wtg,
    const float* __restrict__ Wg, const float* __restrict__ bg,
    float* __restrict__ Kb, float* __restrict__ Vb, float* __restrict__ Qb,
    float* __restrict__ ga, float* __restrict__ ge, float* __restrict__ gt)
{
    __shared__ unsigned short xs_hi[32 * 136];   // row stride 136 (16B-aligned)
    __shared__ unsigned short xs_lo[32 * 136];
    __shared__ unsigned short wt_hi[64 * 136];
    __shared__ unsigned short wt_lo[64 * 136];

    const int tid  = threadIdx.x;
    const int bid  = blockIdx.x;
    const int m    = bid >> 9;
    const int rt   = (bid >> 1) & 255;
    const int ch   = bid & 1;
    const int row0 = rt * 32;

    // stage x tile: 32 rows x 128 fp32 -> bf16 hi/lo
    const float4* x4 = (const float4*)x;
#pragma unroll
    for (int l = 0; l < 4; ++l) {
        int idx = tid + l * 256;          // 0..1023 float4s
        int r = idx >> 5, kq = idx & 31;
        float4 f = x4[(row0 + r) * 32 + kq];
        uint2 hi, lo;
        split2(f.x, f.y, hi.x, lo.x);
        split2(f.z, f.w, hi.y, lo.y);
        *(uint2*)&xs_hi[r * 136 + kq * 4] = hi;
        *(uint2*)&xs_lo[r * 136 + kq * 4] = lo;
    }
    // stage W^T hi/lo: 64 cols x 128 k = 1024 16B-units each
    const uint4* wh4 = (const uint4*)(wtg + m * 16384 + ch * 64 * 128);
    const uint4* wl4 = (const uint4*)(wtg + WT_LO + m * 16384 + ch * 64 * 128);
#pragma unroll
    for (int l = 0; l < 4; ++l) {
        int idx = tid + l * 256;          // 0..1023 units of 8 bf16
        int c = idx >> 4, u = idx & 15;
        *(uint4*)&wt_hi[c * 136 + u * 8] = wh4[c * 16 + u];
        *(uint4*)&wt_lo[c * 136 + u * 8] = wl4[c * 16 + u];
    }
    __syncthreads();

    const int wid  = tid >> 6;
    const int lane = tid & 63;
    const int rg   = wid >> 1;
    const int cg   = wid & 1;
    const int lrow = rg * 16 + (lane & 15);
    const int quad = lane >> 4;

    f32x4 acc[2];
    acc[0] = (f32x4){0.f, 0.f, 0.f, 0.f};
    acc[1] = (f32x4){0.f, 0.f, 0.f, 0.f};

#pragma unroll
    for (int kk = 0; kk < 4; ++kk) {
        bf16x8 ah = *(const bf16x8*)&xs_hi[lrow * 136 + kk * 32 + quad * 8];
        bf16x8 al = *(const bf16x8*)&xs_lo[lrow * 136 + kk * 32 + quad * 8];
#pragma unroll
        for (int ct = 0; ct < 2; ++ct) {
            int cl = cg * 32 + ct * 16 + (lane & 15);
            bf16x8 bh = *(const bf16x8*)&wt_hi[cl * 136 + kk * 32 + quad * 8];
            bf16x8 bl = *(const bf16x8*)&wt_lo[cl * 136 + kk * 32 + quad * 8];
            acc[ct] = __builtin_amdgcn_mfma_f32_16x16x32_bf16(ah, bh, acc[ct], 0, 0, 0);
            acc[ct] = __builtin_amdgcn_mfma_f32_16x16x32_bf16(ah, bl, acc[ct], 0, 0, 0);
            acc[ct] = __builtin_amdgcn_mfma_f32_16x16x32_bf16(al, bh, acc[ct], 0, 0, 0);
        }
    }

    float* dst = (m == 0) ? Kb : (m == 1) ? Vb : Qb;
#pragma unroll
    for (int ct = 0; ct < 2; ++ct) {
        int ocol = ch * 64 + cg * 32 + ct * 16 + (lane & 15);
#pragma unroll
        for (int r4 = 0; r4 < 4; ++r4) {
            int orow = row0 + rg * 16 + quad * 4 + r4;
            dst[orow * ND + ocol] = acc[ct][r4];
        }
    }

    // gates (fp32, from global x — L1-hot) on one block per row-tile
    if (m == 0 && ch == 0 && tid < 96) {
        int r = tid / 3, j = tid % 3;
        float z = bg[j];
        const float* xr = x + (row0 + r) * ND;
#pragma unroll 4
        for (int i = 0; i < ND; ++i)
            z = fmaf(xr[i], Wg[i * 3 + j], z);
        float gate = 1.0f / (1.0f + expf(-z));
        int row = row0 + r;
        float* gd = (j == 0) ? ga : (j == 1) ? ge : gt;
        gd[row] = gate;
    }
}

// ---------------------------------------------------------------------------
// Phase 1: per (b, chunk, d) compose the 16 per-step affine maps into (A, b).
// Thread 0 composes the backward wc map (emit-then-update, gates at index t):
//   step t: Qp' = e_t*Qp, P' = (1-a_t)*P, A' = e_t*A + P'
// ---------------------------------------------------------------------------
__global__ __launch_bounds__(128) void scan_phase1(
    const float* __restrict__ Kb, const float* __restrict__ Vb,
    const float* __restrict__ ga, const float* __restrict__ ge,
    const float* __restrict__ gt, float* __restrict__ ws)
{
    __shared__ float la[NL], le[NL], lt[NL];
    const int tid = threadIdx.x;
    const int b   = blockIdx.x >> 6;
    const int c   = blockIdx.x & 63;
    const int t0  = c * NL;
    const int g0  = b * NS + t0;

    if (tid < 16)       la[tid]      = ga[g0 + tid];
    else if (tid < 32)  le[tid - 16] = ge[g0 + tid - 16];
    else if (tid < 48)  lt[tid - 32] = gt[g0 + tid - 32];
    __syncthreads();

    const int d = tid;
    float A00 = 1.f, A01 = 0.f, A10 = 0.f, A11 = 1.f, B0 = 0.f, B1 = 0.f;
    int base = g0 * ND + d;
#pragma unroll
    for (int t = 0; t < NL; ++t) {
        float k = Kb[base], v = Vb[base];
        float a = la[t], e = le[t], th = lt[t];
        float tk = th * k;
        float gg = -tk * k;
        float h  = tk * v;
        float p  = (1.0f - a) + gg;
        float u0 = e * A10;
        float u1 = e * A11;
        float u2 = fmaf(e, B1, h);
        float n00 = fmaf(p, A00, u0), n10 = fmaf(gg, A00, u0);
        float n01 = fmaf(p, A01, u1), n11 = fmaf(gg, A01, u1);
        float nb0 = fmaf(p, B0, u2),  nb1 = fmaf(gg, B0, u2);
        A00 = n00; A01 = n01; A10 = n10; A11 = n11; B0 = nb0; B1 = nb1;
        base += ND;
    }
    const int pidx = (b * NC + c) * ND + d;
    ws[PL_A00 + pidx] = A00;
    ws[PL_A01 + pidx] = A01;
    ws[PL_A10 + pidx] = A10;
    ws[PL_A11 + pidx] = A11;
    ws[PL_B0  + pidx] = B0;
    ws[PL_B1  + pidx] = B1;

    if (tid == 0) {
        float al = 1.f, be = 1.f, de = 0.f;
#pragma unroll
        for (int t = NL - 1; t >= 0; --t) {
            float e1 = le[t];
            float o1 = 1.0f - la[t];
            de = fmaf(e1, de, o1 * be);
            al *= e1;
            be *= o1;
        }
        ws[PL_WCA + b * NC + c] = al;
        ws[PL_WCB + b * NC + c] = be;
        ws[PL_WCD + b * NC + c] = de;
    }
}

// ---------------------------------------------------------------------------
// Phase 2: scan over chunks (states entering each chunk).
// ---------------------------------------------------------------------------
__global__ __launch_bounds__(64) void scan_phase2(float* __restrict__ ws)
{
    const int tid = threadIdx.x;
    if (blockIdx.x < 16) {
        const int b = blockIdx.x >> 1;
        const int d = (blockIdx.x & 1) * 64 + tid;
        float m = 0.f, s = 0.f;
        int idx = (b * NC) * ND + d;
#pragma unroll 4
        for (int c = 0; c < NC; ++c) {
            ws[PL_MST + idx] = m;
            ws[PL_SST + idx] = s;
            float A00 = ws[PL_A00 + idx], A01 = ws[PL_A01 + idx];
            float A10 = ws[PL_A10 + idx], A11 = ws[PL_A11 + idx];
            float B0  = ws[PL_B0  + idx], B1  = ws[PL_B1  + idx];
            float nm = fmaf(A00, m, fmaf(A01, s, B0));
            float ns = fmaf(A10, m, fmaf(A11, s, B1));
            m = nm; s = ns;
            idx += ND;
        }
    } else if (tid < 8) {
        const int b = tid;
        float Qp = 1.f, P = 1.f, A = 1.f;
        for (int c = NC - 1; c >= 0; --c) {
            ws[PL_WRQ + b * NC + c] = Qp;
            ws[PL_WRP + b * NC + c] = P;
            ws[PL_WRA + b * NC + c] = A;
            float al = ws[PL_WCA + b * NC + c];
            float be = ws[PL_WCB + b * NC + c];
            float de = ws[PL_WCD + b * NC + c];
            float nA = fmaf(al, A, de * P);
            Qp *= al; P *= be; A = nA;
        }
    }
}

// ---------------------------------------------------------------------------
// Phase 3: replay each chunk from its start state; emit y_t, err_t, w_t, c_t.
// ---------------------------------------------------------------------------
__global__ __launch_bounds__(128) void scan_phase3(
    const float* __restrict__ Kb, const float* __restrict__ Vb,
    const float* __restrict__ Qb,
    const float* __restrict__ ga, const float* __restrict__ ge,
    const float* __restrict__ gt,
    float* __restrict__ out, float* __restrict__ errb,
    float* __restrict__ wb,  float* __restrict__ cb,
    float* __restrict__ ws)
{
    __shared__ float la[NL], le[NL], lt[NL];
    const int tid = threadIdx.x;
    const int b   = blockIdx.x >> 6;
    const int c   = blockIdx.x & 63;
    const int t0  = c * NL;
    const int g0  = b * NS + t0;

    if (tid < 16)       la[tid]      = ga[g0 + tid];
    else if (tid < 32)  le[tid - 16] = ge[g0 + tid - 16];
    else if (tid < 48)  lt[tid - 32] = gt[g0 + tid - 32];
    __syncthreads();

    const int d = tid;
    const int pidx = (b * NC + c) * ND + d;
    float m = ws[PL_MST + pidx];
    float s = ws[PL_SST + pidx];
    int base = g0 * ND + d;
#pragma unroll
    for (int t = 0; t < NL; ++t) {
        float k = Kb[base], v = Vb[base], q = Qb[base];
        float a = la[t], e = le[t], th = lt[t];
        float err = fmaf(k, m, -v);
        out[base]  = q * m;
        errb[base] = err;
        float tk = th * k;
        float u  = fmaf(-(tk * k), m, tk * v);
        s = fmaf(e, s, u);
        m = fmaf(1.0f - a, m, s);
        base += ND;
    }

    if (tid == 0) {
        float Qp = ws[PL_WRQ + b * NC + c];
        float P  = ws[PL_WRP + b * NC + c];
        float A  = ws[PL_WRA + b * NC + c];
#pragma unroll
        for (int t = NL - 1; t >= 0; --t) {
            wb[g0 + t] = -lt[t] * Qp;
            cb[g0 + t] = -lt[t] * A;
            float e1 = le[t];
            float o1 = 1.0f - la[t];
            Qp *= e1;
            P  *= o1;
            A   = fmaf(e1, A, P);
        }
    }
}

// ---------------------------------------------------------------------------
// Kernel C: M_final/S_final partials.  C[i][j] = sum_t coeff_t k_t[i] err_t[j]
// ---------------------------------------------------------------------------
__global__ __launch_bounds__(256) void finalgemm_kernel(
    const float* __restrict__ Kb, const float* __restrict__ errb,
    const float* __restrict__ wb, const float* __restrict__ cb,
    float* __restrict__ part)
{
    __shared__ float ks[256 * 16];
    __shared__ float wcs[256 * 2];
    const int tid = threadIdx.x;
    const int bid = blockIdx.x;
    const int b   = bid >> 5;
    const int tc  = (bid >> 3) & 3;
    const int rg  = bid & 7;
    const int bt0 = b * NS + tc * 256;

#pragma unroll
    for (int l = 0; l < 16; ++l) {
        int idx = tid + l * 256;
        int tl = idx >> 4, r = idx & 15;
        ks[tl * 16 + r] = Kb[(bt0 + tl) * ND + rg * 16 + r];
    }
    wcs[tid * 2]     = wb[bt0 + tid];
    wcs[tid * 2 + 1] = cb[bt0 + tid];
    __syncthreads();

    const int j = tid & 127;
    const int h = tid >> 7;
    float accM[8], accS[8];
#pragma unroll
    for (int i = 0; i < 8; ++i) { accM[i] = 0.f; accS[i] = 0.f; }

    int ebase = bt0 * ND + j;
#pragma unroll 2
    for (int t = 0; t < 256; ++t) {
        float ej = errb[ebase];
        float2 wc = *(const float2*)&wcs[t * 2];
        float wej = wc.x * ej, cej = wc.y * ej;
        float4 k0 = *(const float4*)&ks[t * 16 + h * 8];
        float4 k1 = *(const float4*)&ks[t * 16 + h * 8 + 4];
        accS[0] = fmaf(k0.x, wej, accS[0]); accM[0] = fmaf(k0.x, cej, accM[0]);
        accS[1] = fmaf(k0.y, wej, accS[1]); accM[1] = fmaf(k0.y, cej, accM[1]);
        accS[2] = fmaf(k0.z, wej, accS[2]); accM[2] = fmaf(k0.z, cej, accM[2]);
        accS[3] = fmaf(k0.w, wej, accS[3]); accM[3] = fmaf(k0.w, cej, accM[3]);
        accS[4] = fmaf(k1.x, wej, accS[4]); accM[4] = fmaf(k1.x, cej, accM[4]);
        accS[5] = fmaf(k1.y, wej, accS[5]); accM[5] = fmaf(k1.y, cej, accM[5]);
        accS[6] = fmaf(k1.z, wej, accS[6]); accM[6] = fmaf(k1.z, cej, accM[6]);
        accS[7] = fmaf(k1.w, wej, accS[7]); accM[7] = fmaf(k1.w, cej, accM[7]);
        ebase += ND;
    }

    const int robase = rg * 16 + h * 8;
    const unsigned pb = (unsigned)tc * 262144u;
#pragma unroll
    for (int i = 0; i < 8; ++i) {
        int off = b * (ND * ND) + (robase + i) * ND + j;
        part[pb + off]           = accM[i];
        part[pb + 131072u + off] = accS[i];
    }
}

// ---------------------------------------------------------------------------
// Kernel D: reduce 4 t-chunk partials into d_out tail (M_final then S_final)
// ---------------------------------------------------------------------------
__global__ __launch_bounds__(256) void reduce_kernel(
    const float* __restrict__ part, float* __restrict__ outMS)
{
    int idx = blockIdx.x * 256 + threadIdx.x;
    const float4* p = (const float4*)part;
    float4 a = p[idx];
    float4 b = p[idx + 65536];
    float4 c = p[idx + 131072];
    float4 d = p[idx + 196608];
    float4 r;
    r.x = a.x + b.x + c.x + d.x;
    r.y = a.y + b.y + c.y + d.y;
    r.z = a.z + b.z + c.z + d.z;
    r.w = a.w + b.w + c.w + d.w;
    ((float4*)outMS)[idx] = r;
}

extern "C" void kernel_launch(void* const* d_in, const int* in_sizes, int n_in,
                              void* d_out, int out_size, void* d_ws, size_t ws_size,
                              hipStream_t stream) {
    const float* x  = (const float*)d_in[0];
    const float* Wk = (const float*)d_in[1];
    const float* Wv = (const float*)d_in[2];
    const float* Wq = (const float*)d_in[3];
    const float* Wg = (const float*)d_in[4];
    const float* bg = (const float*)d_in[5];
    float* out = (float*)d_out;
    float* ws  = (float*)d_ws;

    float* Kb  = ws + OFF_K;
    float* Qb  = ws + OFF_Q;
    float* Vb  = ws + OFF_V;
    float* Eb  = ws + OFF_E;
    float* ga  = ws + OFF_GA;
    float* ge  = ws + OFF_GE;
    float* gt  = ws + OFF_GT;
    float* wbf = ws + OFF_W;
    float* cbf = ws + OFF_C;
    float* Pb  = ws + OFF_P;
    unsigned short* wtg = (unsigned short*)(ws + OFF_WT);

    wtprep_kernel<<<48, 256, 0, stream>>>(Wk, Wv, Wq, wtg);
    proj_mfma<<<1536, 256, 0, stream>>>(x, wtg, Wg, bg,
                                        Kb, Vb, Qb, ga, ge, gt);
    scan_phase1<<<NB * NC, 128, 0, stream>>>(Kb, Vb, ga, ge, gt, ws);
    scan_phase2<<<17, 64, 0, stream>>>(ws);
    scan_phase3<<<NB * NC, 128, 0, stream>>>(Kb, Vb, Qb, ga, ge, gt,
                                             out, Eb, wbf, cbf, ws);
    finalgemm_kernel<<<256, 256, 0, stream>>>(Kb, Eb, wbf, cbf, Pb);
    reduce_kernel<<<256, 256, 0, stream>>>(Pb, out + 1048576u);
}

// Round 6
// 118.981 us; speedup vs baseline: 2.6572x; 1.1690x over previous
//
#include <hip/hip_runtime.h>
#include <math.h>

// Problem constants: B=8, S=1024, D=128 (fp32 in/out)
#define NB 8
#define NS 1024
#define ND 128
#define NC 64     // chunks
#define NL 16     // steps per chunk

// workspace layout (float offsets)
#define OFF_K  0u
#define OFF_Q  1048576u
#define OFF_V  2097152u
#define OFF_E  3145728u
#define OFF_GA 4194304u
#define OFF_GE 4202496u
#define OFF_GT 4210688u
#define OFF_W  4218880u
#define OFF_C  4227072u
#define OFF_P  4235264u   // scan scratch (formerly partials region)

// chunked-scan scratch
#define PL_A00 (OFF_P)
#define PL_A01 (OFF_P +  65536u)
#define PL_A10 (OFF_P + 131072u)
#define PL_A11 (OFF_P + 196608u)
#define PL_B0  (OFF_P + 262144u)
#define PL_B1  (OFF_P + 327680u)
#define PL_MST (OFF_P + 393216u)
#define PL_SST (OFF_P + 458752u)
#define PL_WCA (OFF_P + 524288u)
#define PL_WCB (OFF_P + 524800u)
#define PL_WCD (OFF_P + 525312u)
#define PL_WRQ (OFF_P + 525824u)
#define PL_WRP (OFF_P + 526336u)
#define PL_WRA (OFF_P + 526848u)
// bf16 W^T hi+lo (3 mats x 128 cols x 128 k each), ushort; 49152 floats space
#define OFF_WT (OFF_P + 532480u)
#define WT_LO  49152u   // ushort offset of lo plane

typedef short bf16x8 __attribute__((ext_vector_type(8)));
typedef float f32x4  __attribute__((ext_vector_type(4)));

static __device__ __forceinline__ unsigned short f2bf(float f) {
    unsigned u = __builtin_bit_cast(unsigned, f);
    unsigned r = (u + 0x7FFFu + ((u >> 16) & 1u)) >> 16;   // RNE
    return (unsigned short)r;
}
static __device__ __forceinline__ float bf2f(unsigned short h) {
    unsigned u = ((unsigned)h) << 16;
    return __builtin_bit_cast(float, u);
}
// split f into hi (bf16) and lo (bf16 of residual)
static __device__ __forceinline__ void split2(float a, float b,
                                              unsigned& hi, unsigned& lo) {
    unsigned short ah = f2bf(a), bh = f2bf(b);
    float ar = a - bf2f(ah), br = b - bf2f(bh);
    hi = (unsigned)ah | ((unsigned)bh << 16);
    lo = (unsigned)f2bf(ar) | ((unsigned)f2bf(br) << 16);
}

// ---------------------------------------------------------------------------
// wtprep: W[k][c] fp32 -> wtg hi/lo planes [m][c][k] bf16 (transposed)
// ---------------------------------------------------------------------------
__global__ __launch_bounds__(256) void wtprep_kernel(
    const float* __restrict__ Wk, const float* __restrict__ Wv,
    const float* __restrict__ Wq, unsigned short* __restrict__ wtg)
{
    const int m    = blockIdx.x >> 4;
    const int cgrp = blockIdx.x & 15;
    const int tid  = threadIdx.x;
    const int cl   = tid >> 5;
    const int h    = tid & 31;
    const int c    = cgrp * 8 + cl;
    const float* W = (m == 0) ? Wk : (m == 1) ? Wv : Wq;

    float f[4];
#pragma unroll
    for (int i = 0; i < 4; ++i)
        f[i] = W[(h * 4 + i) * ND + c];
    uint2 hi, lo;
    split2(f[0], f[1], hi.x, lo.x);
    split2(f[2], f[3], hi.y, lo.y);
    const unsigned base = (unsigned)m * 16384u + (unsigned)c * 128u + (unsigned)h * 4u;
    *(uint2*)&wtg[base]         = hi;
    *(uint2*)&wtg[WT_LO + base] = lo;
}

// ---------------------------------------------------------------------------
// proj_mfma: one of {k,v,q} = x @ W via split-bf16 MFMA 16x16x32
// (3 MFMA terms: hi*hi + hi*lo + lo*hi -> ~fp32 precision).
// grid 1536 = 3 mats x 256 row-tiles(32) x 2 col-halves(64).
// ---------------------------------------------------------------------------
__global__ __launch_bounds__(256) void proj_mfma(
    const float* __restrict__ x, const unsigned short* __restrict__ wtg,
    const float* __restrict__ Wg, const float* __restrict__ bg,
    float* __restrict__ Kb, float* __restrict__ Vb, float* __restrict__ Qb,
    float* __restrict__ ga, float* __restrict__ ge, float* __restrict__ gt)
{
    __shared__ unsigned short xs_hi[32 * 136];
    __shared__ unsigned short xs_lo[32 * 136];
    __shared__ unsigned short wt_hi[64 * 136];
    __shared__ unsigned short wt_lo[64 * 136];

    const int tid  = threadIdx.x;
    const int bid  = blockIdx.x;
    const int m    = bid >> 9;
    const int rt   = (bid >> 1) & 255;
    const int ch   = bid & 1;
    const int row0 = rt * 32;

    const float4* x4 = (const float4*)x;
#pragma unroll
    for (int l = 0; l < 4; ++l) {
        int idx = tid + l * 256;
        int r = idx >> 5, kq = idx & 31;
        float4 f = x4[(row0 + r) * 32 + kq];
        uint2 hi, lo;
        split2(f.x, f.y, hi.x, lo.x);
        split2(f.z, f.w, hi.y, lo.y);
        *(uint2*)&xs_hi[r * 136 + kq * 4] = hi;
        *(uint2*)&xs_lo[r * 136 + kq * 4] = lo;
    }
    const uint4* wh4 = (const uint4*)(wtg + m * 16384 + ch * 64 * 128);
    const uint4* wl4 = (const uint4*)(wtg + WT_LO + m * 16384 + ch * 64 * 128);
#pragma unroll
    for (int l = 0; l < 4; ++l) {
        int idx = tid + l * 256;
        int c = idx >> 4, u = idx & 15;
        *(uint4*)&wt_hi[c * 136 + u * 8] = wh4[c * 16 + u];
        *(uint4*)&wt_lo[c * 136 + u * 8] = wl4[c * 16 + u];
    }
    __syncthreads();

    const int wid  = tid >> 6;
    const int lane = tid & 63;
    const int rg   = wid >> 1;
    const int cg   = wid & 1;
    const int lrow = rg * 16 + (lane & 15);
    const int quad = lane >> 4;

    f32x4 acc[2];
    acc[0] = (f32x4){0.f, 0.f, 0.f, 0.f};
    acc[1] = (f32x4){0.f, 0.f, 0.f, 0.f};

#pragma unroll
    for (int kk = 0; kk < 4; ++kk) {
        bf16x8 ah = *(const bf16x8*)&xs_hi[lrow * 136 + kk * 32 + quad * 8];
        bf16x8 al = *(const bf16x8*)&xs_lo[lrow * 136 + kk * 32 + quad * 8];
#pragma unroll
        for (int ct = 0; ct < 2; ++ct) {
            int cl = cg * 32 + ct * 16 + (lane & 15);
            bf16x8 bh = *(const bf16x8*)&wt_hi[cl * 136 + kk * 32 + quad * 8];
            bf16x8 bl = *(const bf16x8*)&wt_lo[cl * 136 + kk * 32 + quad * 8];
            acc[ct] = __builtin_amdgcn_mfma_f32_16x16x32_bf16(ah, bh, acc[ct], 0, 0, 0);
            acc[ct] = __builtin_amdgcn_mfma_f32_16x16x32_bf16(ah, bl, acc[ct], 0, 0, 0);
            acc[ct] = __builtin_amdgcn_mfma_f32_16x16x32_bf16(al, bh, acc[ct], 0, 0, 0);
        }
    }

    float* dst = (m == 0) ? Kb : (m == 1) ? Vb : Qb;
#pragma unroll
    for (int ct = 0; ct < 2; ++ct) {
        int ocol = ch * 64 + cg * 32 + ct * 16 + (lane & 15);
#pragma unroll
        for (int r4 = 0; r4 < 4; ++r4) {
            int orow = row0 + rg * 16 + quad * 4 + r4;
            dst[orow * ND + ocol] = acc[ct][r4];
        }
    }

    if (m == 0 && ch == 0 && tid < 96) {
        int r = tid / 3, j = tid % 3;
        float z = bg[j];
        const float* xr = x + (row0 + r) * ND;
#pragma unroll 4
        for (int i = 0; i < ND; ++i)
            z = fmaf(xr[i], Wg[i * 3 + j], z);
        float gate = 1.0f / (1.0f + expf(-z));
        int row = row0 + r;
        float* gd = (j == 0) ? ga : (j == 1) ? ge : gt;
        gd[row] = gate;
    }
}

// ---------------------------------------------------------------------------
// Phase 1: per (b, chunk, d) compose the 16 per-step affine maps into (A, b).
// ---------------------------------------------------------------------------
__global__ __launch_bounds__(128) void scan_phase1(
    const float* __restrict__ Kb, const float* __restrict__ Vb,
    const float* __restrict__ ga, const float* __restrict__ ge,
    const float* __restrict__ gt, float* __restrict__ ws)
{
    __shared__ float la[NL], le[NL], lt[NL];
    const int tid = threadIdx.x;
    const int b   = blockIdx.x >> 6;
    const int c   = blockIdx.x & 63;
    const int t0  = c * NL;
    const int g0  = b * NS + t0;

    if (tid < 16)       la[tid]      = ga[g0 + tid];
    else if (tid < 32)  le[tid - 16] = ge[g0 + tid - 16];
    else if (tid < 48)  lt[tid - 32] = gt[g0 + tid - 32];
    __syncthreads();

    const int d = tid;
    float A00 = 1.f, A01 = 0.f, A10 = 0.f, A11 = 1.f, B0 = 0.f, B1 = 0.f;
    int base = g0 * ND + d;
#pragma unroll
    for (int t = 0; t < NL; ++t) {
        float k = Kb[base], v = Vb[base];
        float a = la[t], e = le[t], th = lt[t];
        float tk = th * k;
        float gg = -tk * k;
        float h  = tk * v;
        float p  = (1.0f - a) + gg;
        float u0 = e * A10;
        float u1 = e * A11;
        float u2 = fmaf(e, B1, h);
        float n00 = fmaf(p, A00, u0), n10 = fmaf(gg, A00, u0);
        float n01 = fmaf(p, A01, u1), n11 = fmaf(gg, A01, u1);
        float nb0 = fmaf(p, B0, u2),  nb1 = fmaf(gg, B0, u2);
        A00 = n00; A01 = n01; A10 = n10; A11 = n11; B0 = nb0; B1 = nb1;
        base += ND;
    }
    const int pidx = (b * NC + c) * ND + d;
    ws[PL_A00 + pidx] = A00;
    ws[PL_A01 + pidx] = A01;
    ws[PL_A10 + pidx] = A10;
    ws[PL_A11 + pidx] = A11;
    ws[PL_B0  + pidx] = B0;
    ws[PL_B1  + pidx] = B1;

    if (tid == 0) {
        float al = 1.f, be = 1.f, de = 0.f;
#pragma unroll
        for (int t = NL - 1; t >= 0; --t) {
            float e1 = le[t];
            float o1 = 1.0f - la[t];
            de = fmaf(e1, de, o1 * be);
            al *= e1;
            be *= o1;
        }
        ws[PL_WCA + b * NC + c] = al;
        ws[PL_WCB + b * NC + c] = be;
        ws[PL_WCD + b * NC + c] = de;
    }
}

// ---------------------------------------------------------------------------
// Phase 2: scan over chunks (states entering each chunk).
// ---------------------------------------------------------------------------
__global__ __launch_bounds__(64) void scan_phase2(float* __restrict__ ws)
{
    const int tid = threadIdx.x;
    if (blockIdx.x < 16) {
        const int b = blockIdx.x >> 1;
        const int d = (blockIdx.x & 1) * 64 + tid;
        float m = 0.f, s = 0.f;
        int idx = (b * NC) * ND + d;
#pragma unroll 4
        for (int c = 0; c < NC; ++c) {
            ws[PL_MST + idx] = m;
            ws[PL_SST + idx] = s;
            float A00 = ws[PL_A00 + idx], A01 = ws[PL_A01 + idx];
            float A10 = ws[PL_A10 + idx], A11 = ws[PL_A11 + idx];
            float B0  = ws[PL_B0  + idx], B1  = ws[PL_B1  + idx];
            float nm = fmaf(A00, m, fmaf(A01, s, B0));
            float ns = fmaf(A10, m, fmaf(A11, s, B1));
            m = nm; s = ns;
            idx += ND;
        }
    } else if (tid < 8) {
        const int b = tid;
        float Qp = 1.f, P = 1.f, A = 1.f;
        for (int c = NC - 1; c >= 0; --c) {
            ws[PL_WRQ + b * NC + c] = Qp;
            ws[PL_WRP + b * NC + c] = P;
            ws[PL_WRA + b * NC + c] = A;
            float al = ws[PL_WCA + b * NC + c];
            float be = ws[PL_WCB + b * NC + c];
            float de = ws[PL_WCD + b * NC + c];
            float nA = fmaf(al, A, de * P);
            Qp *= al; P *= be; A = nA;
        }
    }
}

// ---------------------------------------------------------------------------
// Phase 3: replay each chunk from its start state; emit y_t, err_t, w_t, c_t.
// ---------------------------------------------------------------------------
__global__ __launch_bounds__(128) void scan_phase3(
    const float* __restrict__ Kb, const float* __restrict__ Vb,
    const float* __restrict__ Qb,
    const float* __restrict__ ga, const float* __restrict__ ge,
    const float* __restrict__ gt,
    float* __restrict__ out, float* __restrict__ errb,
    float* __restrict__ wb,  float* __restrict__ cb,
    float* __restrict__ ws)
{
    __shared__ float la[NL], le[NL], lt[NL];
    const int tid = threadIdx.x;
    const int b   = blockIdx.x >> 6;
    const int c   = blockIdx.x & 63;
    const int t0  = c * NL;
    const int g0  = b * NS + t0;

    if (tid < 16)       la[tid]      = ga[g0 + tid];
    else if (tid < 32)  le[tid - 16] = ge[g0 + tid - 16];
    else if (tid < 48)  lt[tid - 32] = gt[g0 + tid - 32];
    __syncthreads();

    const int d = tid;
    const int pidx = (b * NC + c) * ND + d;
    float m = ws[PL_MST + pidx];
    float s = ws[PL_SST + pidx];
    int base = g0 * ND + d;
#pragma unroll
    for (int t = 0; t < NL; ++t) {
        float k = Kb[base], v = Vb[base], q = Qb[base];
        float a = la[t], e = le[t], th = lt[t];
        float err = fmaf(k, m, -v);
        out[base]  = q * m;
        errb[base] = err;
        float tk = th * k;
        float u  = fmaf(-(tk * k), m, tk * v);
        s = fmaf(e, s, u);
        m = fmaf(1.0f - a, m, s);
        base += ND;
    }

    if (tid == 0) {
        float Qp = ws[PL_WRQ + b * NC + c];
        float P  = ws[PL_WRP + b * NC + c];
        float A  = ws[PL_WRA + b * NC + c];
#pragma unroll
        for (int t = NL - 1; t >= 0; --t) {
            wb[g0 + t] = -lt[t] * Qp;
            cb[g0 + t] = -lt[t] * A;
            float e1 = le[t];
            float o1 = 1.0f - la[t];
            Qp *= e1;
            P  *= o1;
            A   = fmaf(e1, A, P);
        }
    }
}

// ---------------------------------------------------------------------------
// Kernel C v2: M/S final via fine split-K + atomicAdd.
// grid 1024 = 8b x 16tc(64 t each) x 8rg(16 rows). 256 threads.
// Thread (j=tid&127, h=tid>>7): col j, rows rg*16+h*8..+8, 16 accumulators.
// outMS (out tail) must be pre-zeroed (hipMemsetAsync in kernel_launch).
// ---------------------------------------------------------------------------
__global__ __launch_bounds__(256) void finalgemm_kernel(
    const float* __restrict__ Kb, const float* __restrict__ errb,
    const float* __restrict__ wb, const float* __restrict__ cb,
    float* __restrict__ outMS)
{
    __shared__ float ks[64 * 16];
    __shared__ float wcs[64 * 2];
    const int tid = threadIdx.x;
    const int bid = blockIdx.x;
    const int b   = bid >> 7;
    const int tc  = (bid >> 3) & 15;
    const int rg  = bid & 7;
    const int bt0 = b * NS + tc * 64;

    // stage ks: 64 t x 16 rows = 256 float4s, one per thread
    {
        int tl = tid >> 2, r4 = tid & 3;
        *(float4*)&ks[tl * 16 + r4 * 4] =
            *(const float4*)&Kb[(bt0 + tl) * ND + rg * 16 + r4 * 4];
    }
    if (tid < 64) {
        wcs[tid * 2]     = wb[bt0 + tid];
        wcs[tid * 2 + 1] = cb[bt0 + tid];
    }
    __syncthreads();

    const int j = tid & 127;
    const int h = tid >> 7;
    float accM[8], accS[8];
#pragma unroll
    for (int i = 0; i < 8; ++i) { accM[i] = 0.f; accS[i] = 0.f; }

    int ebase = bt0 * ND + j;
#pragma unroll 4
    for (int t = 0; t < 64; ++t) {
        float ej = errb[ebase];
        float2 wc = *(const float2*)&wcs[t * 2];
        float wej = wc.x * ej, cej = wc.y * ej;
        float4 k0 = *(const float4*)&ks[t * 16 + h * 8];
        float4 k1 = *(const float4*)&ks[t * 16 + h * 8 + 4];
        accS[0] = fmaf(k0.x, wej, accS[0]); accM[0] = fmaf(k0.x, cej, accM[0]);
        accS[1] = fmaf(k0.y, wej, accS[1]); accM[1] = fmaf(k0.y, cej, accM[1]);
        accS[2] = fmaf(k0.z, wej, accS[2]); accM[2] = fmaf(k0.z, cej, accM[2]);
        accS[3] = fmaf(k0.w, wej, accS[3]); accM[3] = fmaf(k0.w, cej, accM[3]);
        accS[4] = fmaf(k1.x, wej, accS[4]); accM[4] = fmaf(k1.x, cej, accM[4]);
        accS[5] = fmaf(k1.y, wej, accS[5]); accM[5] = fmaf(k1.y, cej, accM[5]);
        accS[6] = fmaf(k1.z, wej, accS[6]); accM[6] = fmaf(k1.z, cej, accM[6]);
        accS[7] = fmaf(k1.w, wej, accS[7]); accM[7] = fmaf(k1.w, cej, accM[7]);
        ebase += ND;
    }

    const int robase = rg * 16 + h * 8;
#pragma unroll
    for (int i = 0; i < 8; ++i) {
        int off = b * (ND * ND) + (robase + i) * ND + j;
        atomicAdd(&outMS[off], accM[i]);
        atomicAdd(&outMS[131072u + off], accS[i]);
    }
}

extern "C" void kernel_launch(void* const* d_in, const int* in_sizes, int n_in,
                              void* d_out, int out_size, void* d_ws, size_t ws_size,
                              hipStream_t stream) {
    const float* x  = (const float*)d_in[0];
    const float* Wk = (const float*)d_in[1];
    const float* Wv = (const float*)d_in[2];
    const float* Wq = (const float*)d_in[3];
    const float* Wg = (const float*)d_in[4];
    const float* bg = (const float*)d_in[5];
    float* out = (float*)d_out;
    float* ws  = (float*)d_ws;

    float* Kb  = ws + OFF_K;
    float* Qb  = ws + OFF_Q;
    float* Vb  = ws + OFF_V;
    float* Eb  = ws + OFF_E;
    float* ga  = ws + OFF_GA;
    float* ge  = ws + OFF_GE;
    float* gt  = ws + OFF_GT;
    float* wbf = ws + OFF_W;
    float* cbf = ws + OFF_C;
    unsigned short* wtg = (unsigned short*)(ws + OFF_WT);

    // zero the M/S output tail (atomics accumulate into it)
    hipMemsetAsync(out + 1048576u, 0, 262144u * sizeof(float), stream);

    wtprep_kernel<<<48, 256, 0, stream>>>(Wk, Wv, Wq, wtg);
    proj_mfma<<<1536, 256, 0, stream>>>(x, wtg, Wg, bg,
                                        Kb, Vb, Qb, ga, ge, gt);
    scan_phase1<<<NB * NC, 128, 0, stream>>>(Kb, Vb, ga, ge, gt, ws);
    scan_phase2<<<17, 64, 0, stream>>>(ws);
    scan_phase3<<<NB * NC, 128, 0, stream>>>(Kb, Vb, Qb, ga, ge, gt,
                                             out, Eb, wbf, cbf, ws);
    finalgemm_kernel<<<1024, 256, 0, stream>>>(Kb, Eb, wbf, cbf,
                                               out + 1048576u);
}